// Round 2
// baseline (61.073 us; speedup 1.0000x reference)
//
#include <hip/hip_runtime.h>

// out[i] = cos^4( dot(x[i,:], W[0,:]) + b[0] )
//
// Derivation (Heisenberg picture): measured op is Z on wire 0; wire 0 is only
// ever a CNOT *control*, so Chain† Z0 Chain = Z0, and every Y0 branch produced
// by RX conjugation picks up an X-string on wires >=1 that never cancels
// (RX keeps X invariant; CNOT-chain conjugation maps X-strings to X-strings).
// Only the pure-Z0 branch survives <0..0|.|0..0>, with coefficient
// cos(theta0)^DEPTH = cos^4(theta0).  Verified by hand at n=2, DEPTH=2.

#define K 512              // feature dim
#define ROWS_PER_WAVE 4    // 4 rows per wave -> 8 x-loads in flight per wave
#define WAVES_PER_BLOCK 4
#define ROWS_PER_BLOCK (ROWS_PER_WAVE * WAVES_PER_BLOCK)   // 16

// clang-native vector type: __builtin_nontemporal_load requires a pointer to
// scalar/vector-of-scalar, not HIP's float4 class type.
typedef float v4f __attribute__((ext_vector_type(4)));

__global__ __launch_bounds__(256) void qg_expval_kernel(
    const float* __restrict__ x,   // [B, 512]
    const float* __restrict__ W,   // [12, 512] — only row 0 used
    const float* __restrict__ b,   // [12]      — only b[0] used
    float* __restrict__ out,       // [B]
    int B)
{
    const int wave = threadIdx.x >> 6;
    const int lane = threadIdx.x & 63;
    const int row0 = (blockIdx.x * WAVES_PER_BLOCK + wave) * ROWS_PER_WAVE;
    if (row0 >= B) return;

    // W row 0: 512 floats = 64 lanes * 2 * v4f. Reused by every wave on the
    // chip -> leave it cacheable (L2-resident after the first block touches it).
    const v4f* w4 = (const v4f*)W;
    const v4f w0 = w4[lane];
    const v4f w1 = w4[64 + lane];

    // Issue ALL x loads up front: 8 outstanding 16B/lane nontemporal loads.
    // x is read exactly once chip-wide -> nt keeps it from displacing W in L2.
    v4f a[ROWS_PER_WAVE][2];
    #pragma unroll
    for (int r = 0; r < ROWS_PER_WAVE; ++r) {
        const v4f* xr = (const v4f*)(x + (size_t)(row0 + r) * K);
        a[r][0] = __builtin_nontemporal_load(&xr[lane]);
        a[r][1] = __builtin_nontemporal_load(&xr[64 + lane]);
    }

    // Per-lane partial dot products: 4 independent chains (ILP).
    float p[ROWS_PER_WAVE];
    #pragma unroll
    for (int r = 0; r < ROWS_PER_WAVE; ++r) {
        p[r] = a[r][0][0] * w0[0] + a[r][0][1] * w0[1]
             + a[r][0][2] * w0[2] + a[r][0][3] * w0[3]
             + a[r][1][0] * w1[0] + a[r][1][1] * w1[1]
             + a[r][1][2] * w1[2] + a[r][1][3] * w1[3];
    }

    // wave-64 butterfly reduction, 4 independent chains pipeline instead of
    // serializing on one dependency chain.
    #pragma unroll
    for (int off = 32; off > 0; off >>= 1) {
        #pragma unroll
        for (int r = 0; r < ROWS_PER_WAVE; ++r)
            p[r] += __shfl_xor(p[r], off, 64);
    }

    if (lane == 0) {
        const float bb = b[0];
        v4f o;
        float c;
        c = cosf(p[0] + bb); c = c * c; o[0] = c * c;
        c = cosf(p[1] + bb); c = c * c; o[1] = c * c;
        c = cosf(p[2] + bb); c = c * c; o[2] = c * c;
        c = cosf(p[3] + bb); c = c * c; o[3] = c * c;
        // rows are contiguous -> single 16B store replaces 4 scalar stores
        *(v4f*)(out + row0) = o;
    }
}

extern "C" void kernel_launch(void* const* d_in, const int* in_sizes, int n_in,
                              void* d_out, int out_size, void* d_ws, size_t ws_size,
                              hipStream_t stream) {
    const float* x = (const float*)d_in[0];   // [B, 512]
    const float* W = (const float*)d_in[1];   // [12, 512]
    const float* b = (const float*)d_in[2];   // [12]
    float* out = (float*)d_out;               // [B]

    const int B = in_sizes[0] / K;            // 4096
    const int grid = (B + ROWS_PER_BLOCK - 1) / ROWS_PER_BLOCK;  // 256 blocks

    qg_expval_kernel<<<grid, 256, 0, stream>>>(x, W, b, out, B);
}